// Round 9
// baseline (547.305 us; speedup 1.0000x reference)
//
#include <hip/hip_runtime.h>
#include <stdint.h>

#define DEV __device__ __forceinline__

typedef __attribute__((ext_vector_type(8))) short bf16x8;   // 8 bf16 = 4 VGPRs
typedef __attribute__((ext_vector_type(4))) float f32x4;

// ---------- bf16 bit helpers ----------
DEV float bf2f(uint16_t u) { return __uint_as_float(((uint32_t)u) << 16); }
DEV uint16_t f2bfbits(float f) {          // round-to-nearest-even
    uint32_t x = __float_as_uint(f);
    uint32_t r = x + 0x7fffu + ((x >> 16) & 1u);
    return (uint16_t)(r >> 16);
}
DEV void stv(uint16_t* p, float v) { *p = f2bfbits(v); }
DEV void stv(float* p, float v) { *p = v; }

template<int C> DEV void ldbf(const uint16_t* p, float* f);
template<> DEV void ldbf<2>(const uint16_t* p, float* f) {
    uint32_t v = *reinterpret_cast<const uint32_t*>(p);
    f[0] = __uint_as_float(v << 16); f[1] = __uint_as_float(v & 0xffff0000u);
}
template<> DEV void ldbf<4>(const uint16_t* p, float* f) {
    uint2 v = *reinterpret_cast<const uint2*>(p);
    f[0] = __uint_as_float(v.x << 16); f[1] = __uint_as_float(v.x & 0xffff0000u);
    f[2] = __uint_as_float(v.y << 16); f[3] = __uint_as_float(v.y & 0xffff0000u);
}

// async global->LDS, 16B per lane; LDS dest = wave-uniform base + lane*16
DEV void gl16(const uint16_t* g, uint8_t* l) {
    __builtin_amdgcn_global_load_lds(
        (const __attribute__((address_space(1))) uint32_t*)g,
        (__attribute__((address_space(3))) uint32_t*)l, 16, 0, 0);
}

// ---------------------- CSR build ----------------------
__global__ void k_count(const int* __restrict__ dst, int e, int* __restrict__ deg) {
    int i = blockIdx.x * 256 + threadIdx.x;
    if (i < e) atomicAdd(&deg[dst[i]], 1);
}

__global__ void k_block_sums(const int* __restrict__ deg, int n, int* __restrict__ bsum) {
    __shared__ int sm[256];
    int base = blockIdx.x * 1024;
    int s = 0;
    for (int i = threadIdx.x; i < 1024; i += 256) {
        int g = base + i;
        if (g < n) s += deg[g];
    }
    sm[threadIdx.x] = s; __syncthreads();
    for (int o = 128; o > 0; o >>= 1) {
        if (threadIdx.x < o) sm[threadIdx.x] += sm[threadIdx.x + o];
        __syncthreads();
    }
    if (threadIdx.x == 0) bsum[blockIdx.x] = sm[0];
}

__global__ void k_scan_bsums(int* bsum, int nb) {
    __shared__ int sm[256];
    int t = threadIdx.x;
    int v = (t < nb) ? bsum[t] : 0;
    sm[t] = v; __syncthreads();
    for (int o = 1; o < 256; o <<= 1) {
        int add = (t >= o) ? sm[t - o] : 0;
        __syncthreads();
        sm[t] += add;
        __syncthreads();
    }
    if (t < nb) bsum[t] = (t == 0) ? 0 : sm[t - 1];
}

__global__ void k_scan_final(const int* __restrict__ deg, int n,
                             const int* __restrict__ bsum, int* __restrict__ offs,
                             int* __restrict__ cursor) {
    __shared__ int sm[256];
    int t = threadIdx.x;
    int i0 = blockIdx.x * 1024 + t * 4;
    int d0 = (i0     < n) ? deg[i0]     : 0;
    int d1 = (i0 + 1 < n) ? deg[i0 + 1] : 0;
    int d2 = (i0 + 2 < n) ? deg[i0 + 2] : 0;
    int d3 = (i0 + 3 < n) ? deg[i0 + 3] : 0;
    int ts = d0 + d1 + d2 + d3;
    sm[t] = ts; __syncthreads();
    for (int o = 1; o < 256; o <<= 1) {
        int add = (t >= o) ? sm[t - o] : 0;
        __syncthreads();
        sm[t] += add;
        __syncthreads();
    }
    int e0 = bsum[blockIdx.x] + ((t == 0) ? 0 : sm[t - 1]);
    int e1 = e0 + d0, e2 = e1 + d1, e3 = e2 + d2, e4 = e3 + d3;
    if (i0     < n) { offs[i0]     = e0; cursor[i0]     = e0; }
    if (i0 + 1 < n) { offs[i0 + 1] = e1; cursor[i0 + 1] = e1; }
    if (i0 + 2 < n) { offs[i0 + 2] = e2; cursor[i0 + 2] = e2; }
    if (i0 + 3 < n) { offs[i0 + 3] = e3; cursor[i0 + 3] = e3; }
    if (i0 <= n - 1 && n - 1 < i0 + 4) offs[n] = e4;  // total
}

__global__ void k_scatter(const int* __restrict__ src, const int* __restrict__ dst, int e,
                          int* __restrict__ cursor, int* __restrict__ csr) {
    int i = blockIdx.x * 256 + threadIdx.x;
    if (i < e) {
        int p = atomicAdd(&cursor[dst[i]], 1);
        csr[p] = src[i];
    }
}

// ---------------------- fp32 -> bf16 convert ----------------------
__global__ void k_f2b(const float* __restrict__ in, uint16_t* __restrict__ o, int n4) {
    int i = blockIdx.x * 256 + threadIdx.x;
    if (i < n4) {
        float4 v = reinterpret_cast<const float4*>(in)[i];
        uint2 w;
        w.x = f2bfbits(v.x) | ((uint32_t)f2bfbits(v.y) << 16);
        w.y = f2bfbits(v.z) | ((uint32_t)f2bfbits(v.w) << 16);
        reinterpret_cast<uint2*>(o)[i] = w;
    }
}

// ---------------------- fused weight prep: transpose fp32 [K][Dreal] -> bf16 wt[n][koff+k] ----------------------
struct PrepSeg { const float* W; uint16_t* wt; int K, Dreal, koff, ldk, start, end; };
struct PrepAll { PrepSeg s[8]; };

__global__ void k_prep_all(PrepAll P, int total) {
    int idx = blockIdx.x * 256 + threadIdx.x;
    if (idx >= total) return;
#pragma unroll
    for (int i = 0; i < 8; ++i) {
        if (idx >= P.s[i].start && idx < P.s[i].end) {
            int loc = idx - P.s[i].start;
            int K = P.s[i].K;
            int nn = loc / K, k = loc - nn * K;
            float v = (nn < P.s[i].Dreal) ? P.s[i].W[(size_t)k * P.s[i].Dreal + nn] : 0.f;
            P.s[i].wt[(size_t)nn * P.s[i].ldk + P.s[i].koff + k] = f2bfbits(v);
        }
    }
}

// ---------------------- max-aggregation (bf16 in/out) ----------------------
template<int D, bool MAXAGG>
__global__ __launch_bounds__(256) void k_aggr(const uint16_t* __restrict__ X,
                                              const int* __restrict__ offs,
                                              const int* __restrict__ csr,
                                              int n, uint16_t* __restrict__ out) {
    constexpr int C = D / 64;
    int lane = threadIdx.x & 63;
    int node = blockIdx.x * 4 + (threadIdx.x >> 6);
    if (node >= n) return;
    int beg = offs[node], end = offs[node + 1];
    float acc[C];
#pragma unroll
    for (int c = 0; c < C; c++) acc[c] = 0.f;
    const size_t loff = (size_t)lane * C;
    int i = beg;
    for (; i + 3 < end; i += 4) {             // 4 gathers in flight
        int s0 = csr[i], s1 = csr[i + 1], s2 = csr[i + 2], s3 = csr[i + 3];
        float f0[C], f1[C], f2[C], f3[C];
        ldbf<C>(X + (size_t)s0 * D + loff, f0);
        ldbf<C>(X + (size_t)s1 * D + loff, f1);
        ldbf<C>(X + (size_t)s2 * D + loff, f2);
        ldbf<C>(X + (size_t)s3 * D + loff, f3);
#pragma unroll
        for (int c = 0; c < C; c++) {
            if (MAXAGG) {
                acc[c] = fmaxf(acc[c], fmaxf(fmaxf(f0[c], f1[c]), fmaxf(f2[c], f3[c])));
            } else {
                acc[c] += (f0[c] + f1[c]) + (f2[c] + f3[c]);
            }
        }
    }
    for (; i < end; ++i) {
        int s = csr[i];
        float f[C];
        ldbf<C>(X + (size_t)s * D + loff, f);
#pragma unroll
        for (int c = 0; c < C; c++)
            acc[c] = MAXAGG ? fmaxf(acc[c], f[c]) : (acc[c] + f[c]);
    }
    int d = end - beg; if (d < 1) d = 1;
    float scale = MAXAGG ? 1.f : (1.f / (float)d);
    uint16_t* q = out + (size_t)node * D + loff;
    if constexpr (C == 2) {
        uint32_t v = f2bfbits(acc[0] * scale) | ((uint32_t)f2bfbits(acc[1] * scale) << 16);
        *reinterpret_cast<uint32_t*>(q) = v;
    } else {
        uint2 v;
        v.x = f2bfbits(acc[0] * scale) | ((uint32_t)f2bfbits(acc[1] * scale) << 16);
        v.y = f2bfbits(acc[2] * scale) | ((uint32_t)f2bfbits(acc[3] * scale) << 16);
        *reinterpret_cast<uint2*>(q) = v;
    }
}

// ---------------------- mean-aggregate(Y) + Z + LN + ReLU  (SAGE-mean reordered) ----------------------
// YZ = [N][256] bf16: cols 0-127 = Y = X@Wl, cols 128-255 = Z = X@Wr + bl.
__global__ __launch_bounds__(256) void k_aggr_ln(const uint16_t* __restrict__ YZ,
                                                 const int* __restrict__ offs,
                                                 const int* __restrict__ csr,
                                                 const float* __restrict__ g,
                                                 const float* __restrict__ b,
                                                 int n, uint16_t* __restrict__ out) {
    int lane = threadIdx.x & 63;
    int node = blockIdx.x * 4 + (threadIdx.x >> 6);
    if (node >= n) return;
    int beg = offs[node], end = offs[node + 1];
    float a0 = 0.f, a1 = 0.f;
    const size_t loff = (size_t)lane * 2;
    int i = beg;
    for (; i + 3 < end; i += 4) {             // 4 gathers in flight
        int s0 = csr[i], s1 = csr[i + 1], s2 = csr[i + 2], s3 = csr[i + 3];
        float f0[2], f1[2], f2[2], f3[2];
        ldbf<2>(YZ + (size_t)s0 * 256 + loff, f0);
        ldbf<2>(YZ + (size_t)s1 * 256 + loff, f1);
        ldbf<2>(YZ + (size_t)s2 * 256 + loff, f2);
        ldbf<2>(YZ + (size_t)s3 * 256 + loff, f3);
        a0 += (f0[0] + f1[0]) + (f2[0] + f3[0]);
        a1 += (f0[1] + f1[1]) + (f2[1] + f3[1]);
    }
    for (; i < end; ++i) {
        int s = csr[i];
        float f[2];
        ldbf<2>(YZ + (size_t)s * 256 + loff, f);
        a0 += f[0]; a1 += f[1];
    }
    int d = end - beg; if (d < 1) d = 1;
    float scale = 1.f / (float)d;
    float z[2];
    ldbf<2>(YZ + (size_t)node * 256 + 128 + loff, z);
    float v0 = a0 * scale + z[0];
    float v1 = a1 * scale + z[1];
    float s = v0 + v1, s2 = v0 * v0 + v1 * v1;
#pragma unroll
    for (int o = 1; o < 64; o <<= 1) { s += __shfl_xor(s, o); s2 += __shfl_xor(s2, o); }
    float mean = s * (1.f / 128.f);
    float var = s2 * (1.f / 128.f) - mean * mean;
    float inv = rsqrtf(var + 1e-5f);
    float y0 = fmaxf((v0 - mean) * inv * g[loff]     + b[loff],     0.f);
    float y1 = fmaxf((v1 - mean) * inv * g[loff + 1] + b[loff + 1], 0.f);
    uint32_t w = f2bfbits(y0) | ((uint32_t)f2bfbits(y1) << 16);
    *reinterpret_cast<uint32_t*>(out + (size_t)node * 128 + loff) = w;
}

// ---------------------- MFMA GEMM: W LDS-resident + depth-PD register prefetch of A ----------------------
// 512 threads = 8 waves of 64x64. NCW=DB/64 col-groups, NRW=8/NCW row-groups (ROWS=NRW*64).
// grid.y col-splits the output: col0 = blockIdx.y*DB (only for LN-free layers).
// W staged ONCE via global_load_lds into padded planes (WPL = DB*16+32 -> bank phases 0/32/64/96),
// single barrier. K-loop: A frags global->VGPR with an explicit depth-PD rotating prefetch
// (af[s%PD], fully unrolled -> static indices), W frags from LDS. No barriers in the loop.
// A frag: row=lane&15, k=(lane>>4)*8+j ; B frag: col=lane&15 ; C/D: col=lane&15, row=(lane>>4)*4+reg.
template<int KPER, int DOUT, int DB, int ROWS, bool DUAL, bool LN, bool ZBIAS, typename TO>
__global__ __launch_bounds__(512) void k_mf(const uint16_t* __restrict__ A0,
                                            const uint16_t* __restrict__ A1,
                                            const uint16_t* __restrict__ WT,
                                            const float* __restrict__ bias,
                                            const float* __restrict__ g,
                                            const float* __restrict__ bvec,
                                            int n, TO* __restrict__ out) {
    constexpr int KEFF = KPER * (DUAL ? 2 : 1);
    constexpr int NCW = DB / 64;
    constexpr int NRW = ROWS / 64;
    static_assert(NCW * NRW == 8, "8 waves of 64x64");
    constexpr int NST = KEFF / 32;        // k-steps
    constexpr int PD  = NST < 4 ? NST : 4; // prefetch depth
    constexpr int WPL = DB * 16 + 32;     // padded LDS plane bytes (8-k chunk)
    constexpr int NPL = KEFF / 8;         // planes
    constexpr int WHB = DB / 64;          // 1KB chunks per plane
    constexpr int TCH = NPL * WHB;
    __shared__ __align__(16) uint8_t wL[NPL * WPL];

    int tid = threadIdx.x;
    int lane = tid & 63, wid = tid >> 6;
    int lr = lane & 15, kb = lane >> 4;
    int row0 = blockIdx.x * ROWS;
    int col0 = blockIdx.y * DB;
    int wr = wid / NCW, wc = wid % NCW;

    // stage ALL of W[col0..col0+DB) into LDS (async DMA; drained by barrier)
    const uint16_t* WTb = WT + (size_t)col0 * KEFF;
    for (int p = wid; p < TCH; p += 8) {
        int cp = p / WHB, h = p % WHB;
        gl16(WTb + (size_t)(h * 64 + lane) * KEFF + cp * 8, wL + cp * WPL + h * 1024);
    }

    // A row bases (clamped; constant over k)
    const uint16_t* arow0[4];
    const uint16_t* arow1[4];
#pragma unroll
    for (int m = 0; m < 4; ++m) {
        int row = row0 + wr * 64 + m * 16 + lr;
        if (row >= n) row = n - 1;
        arow0[m] = A0 + (size_t)row * KPER;
        if constexpr (DUAL) arow1[m] = A1 + (size_t)row * KPER;
    }

    bf16x8 af[PD][4];
    auto loadA = [&](int s, int slot) {
        int kt = s * 32;
        bool hi = DUAL && kt >= KPER;
        int kk = hi ? kt - KPER : kt;
#pragma unroll
        for (int m = 0; m < 4; ++m) {
            const uint16_t* ap = (DUAL && hi) ? arow1[m] : arow0[m];
            af[slot][m] = *reinterpret_cast<const bf16x8*>(ap + kk + kb * 8);
        }
    };

    // prologue: fill the pipeline (loads in flight across the barrier)
#pragma unroll
    for (int s = 0; s < PD; ++s) loadA(s, s);

    __syncthreads();   // W LDS-resident from here on

    f32x4 acc[4][4] = {};   // [m: row 16-tile][q: col 16-tile]
#pragma unroll
    for (int s = 0; s < NST; ++s) {
        bf16x8 wf[4];
#pragma unroll
        for (int q = 0; q < 4; ++q)
            wf[q] = *reinterpret_cast<const bf16x8*>(
                wL + (size_t)(s * 4 + kb) * WPL + (wc * 64 + q * 16 + lr) * 16);
        const int slot = s % PD;   // static after full unroll
#pragma unroll
        for (int m = 0; m < 4; ++m)
#pragma unroll
            for (int q = 0; q < 4; ++q)
                acc[m][q] = __builtin_amdgcn_mfma_f32_16x16x32_bf16(af[slot][m], wf[q], acc[m][q], 0, 0, 0);
        if (s + PD < NST) loadA(s + PD, slot);   // refill slot for step s+PD
    }

    // ---- epilogue: bias (+ LN + ReLU), store ----
    float gv[4], bvv[4];
#pragma unroll
    for (int q = 0; q < 4; ++q) {
        int col = col0 + wc * 64 + q * 16 + lr;
        float bsv;
        if constexpr (ZBIAS) {
            bsv = (col >= DOUT / 2) ? bias[col - DOUT / 2] : 0.f;
        } else {
            bsv = (col < DOUT) ? bias[col] : 0.f;
        }
#pragma unroll
        for (int m = 0; m < 4; ++m)
#pragma unroll
            for (int r = 0; r < 4; ++r) acc[m][q][r] += bsv;
        if constexpr (LN) { gv[q] = g[col]; bvv[q] = bvec[col]; }
    }
    if constexpr (LN) {
        float sA[4][4], s2A[4][4];
#pragma unroll
        for (int m = 0; m < 4; ++m) {
#pragma unroll
            for (int r = 0; r < 4; ++r) { sA[m][r] = 0.f; s2A[m][r] = 0.f; }
#pragma unroll
            for (int q = 0; q < 4; ++q)
#pragma unroll
                for (int r = 0; r < 4; ++r) { float v = acc[m][q][r]; sA[m][r] += v; s2A[m][r] += v * v; }
#pragma unroll
            for (int r = 0; r < 4; ++r)
#pragma unroll
                for (int o = 1; o < 16; o <<= 1) {   // reduce within 16-lane col group
                    sA[m][r] += __shfl_xor(sA[m][r], o);
                    s2A[m][r] += __shfl_xor(s2A[m][r], o);
                }
        }
        if constexpr (NCW == 1) {
#pragma unroll
            for (int m = 0; m < 4; ++m)
#pragma unroll
                for (int r = 0; r < 4; ++r) {
                    float mean = sA[m][r] / DOUT;
                    float var = s2A[m][r] / DOUT - mean * mean;
                    float inv = rsqrtf(var + 1e-5f);
#pragma unroll
                    for (int q = 0; q < 4; ++q)
                        acc[m][q][r] = fmaxf((acc[m][q][r] - mean) * inv * gv[q] + bvv[q], 0.f);
                }
        } else {
            float* smS  = reinterpret_cast<float*>(wL);   // W dead after k-loop
            float* smS2 = smS + ROWS * NCW;
            __syncthreads();   // all waves done reading W
            if (lr == 0) {
#pragma unroll
                for (int m = 0; m < 4; ++m)
#pragma unroll
                    for (int r = 0; r < 4; ++r) {
                        int rg = wr * 64 + m * 16 + kb * 4 + r;
                        smS[rg * NCW + wc]  = sA[m][r];
                        smS2[rg * NCW + wc] = s2A[m][r];
                    }
            }
            __syncthreads();
#pragma unroll
            for (int m = 0; m < 4; ++m)
#pragma unroll
                for (int r = 0; r < 4; ++r) {
                    int rg = wr * 64 + m * 16 + kb * 4 + r;
                    float ss = 0.f, ss2 = 0.f;
#pragma unroll
                    for (int w2 = 0; w2 < NCW; ++w2) { ss += smS[rg * NCW + w2]; ss2 += smS2[rg * NCW + w2]; }
                    float mean = ss / DOUT;
                    float var = ss2 / DOUT - mean * mean;
                    float inv = rsqrtf(var + 1e-5f);
#pragma unroll
                    for (int q = 0; q < 4; ++q)
                        acc[m][q][r] = fmaxf((acc[m][q][r] - mean) * inv * gv[q] + bvv[q], 0.f);
                }
        }
    }
#pragma unroll
    for (int m = 0; m < 4; ++m)
#pragma unroll
        for (int r = 0; r < 4; ++r) {
            int row = row0 + wr * 64 + m * 16 + kb * 4 + r;
            if (row < n) {
#pragma unroll
                for (int q = 0; q < 4; ++q) {
                    int col = col0 + wc * 64 + q * 16 + lr;
                    if (col < DOUT)
                        stv(out + (size_t)row * DOUT + col, acc[m][q][r]);
                }
            }
        }
}

// ---------------------- launcher ----------------------
extern "C" void kernel_launch(void* const* d_in, const int* in_sizes, int n_in,
                              void* d_out, int out_size, void* d_ws, size_t ws_size,
                              hipStream_t stream) {
    const float* x     = (const float*)d_in[0];
    const int*   src   = (const int*)d_in[1];
    const int*   dst   = (const int*)d_in[2];
    const float* s1_wl = (const float*)d_in[3];
    const float* s1_bl = (const float*)d_in[4];
    const float* s1_wr = (const float*)d_in[5];
    const float* ln1_g = (const float*)d_in[6];
    const float* ln1_b = (const float*)d_in[7];
    const float* s2_wl = (const float*)d_in[8];
    const float* s2_bl = (const float*)d_in[9];
    const float* s2_wr = (const float*)d_in[10];
    const float* ln2_g = (const float*)d_in[11];
    const float* ln2_b = (const float*)d_in[12];
    const float* s3_wl = (const float*)d_in[13];
    const float* s3_bl = (const float*)d_in[14];
    const float* s3_wr = (const float*)d_in[15];
    const float* ln3_g = (const float*)d_in[16];
    const float* ln3_b = (const float*)d_in[17];
    const float* l1_w  = (const float*)d_in[18];
    const float* l1_b  = (const float*)d_in[19];
    const float* ln4_g = (const float*)d_in[20];
    const float* ln4_b = (const float*)d_in[21];
    const float* lo_w  = (const float*)d_in[22];
    const float* lo_b  = (const float*)d_in[23];
    float* out = (float*)d_out;

    const int N = in_sizes[0] / 128;
    const int E = in_sizes[1];
    (void)n_in; (void)out_size; (void)ws_size;

    char* w = (char*)d_ws;
    size_t off = 0;
    auto alloc = [&](size_t bytes) -> void* {
        void* p = w + off;
        off = (off + bytes + 255) & ~(size_t)255;
        return p;
    };
    int* deg    = (int*)alloc((size_t)N * 4);
    int* offs   = (int*)alloc((size_t)(N + 1) * 4);
    int* cursor = (int*)alloc((size_t)N * 4);
    int* bsum   = (int*)alloc(1024 * 4);
    int* csr    = (int*)alloc((size_t)E * 4);
    uint16_t* wt1 = (uint16_t*)alloc(256 * 128 * 2);   // [256][128]: rows 0-127 Wl1^T, 128-255 Wr1^T
    uint16_t* wt2 = (uint16_t*)alloc(256 * 256 * 2);   // [256][256]: K-concat [Wl2;Wr2]
    uint16_t* wt3 = (uint16_t*)alloc(256 * 256 * 2);   // [256][256]: rows 0-127 Wl3^T, 128-255 Wr3^T
    uint16_t* wt4 = (uint16_t*)alloc(64 * 128 * 2);    // [64][128]
    uint16_t* wt5 = (uint16_t*)alloc(128 * 64 * 2);    // [128][64] (cols 100..127 zero)
    uint16_t* xb    = (uint16_t*)alloc((size_t)N * 128 * 2);
    uint16_t* YZ    = (uint16_t*)alloc((size_t)N * 256 * 2);  // [Y|Z] for layers 1 and 3
    uint16_t* h1    = (uint16_t*)alloc((size_t)N * 128 * 2);
    uint16_t* aggrB = (uint16_t*)alloc((size_t)N * 128 * 2);  // max-aggr output; reused as h4
    uint16_t* h2    = (uint16_t*)alloc((size_t)N * 256 * 2);
    uint16_t* h3    = (uint16_t*)alloc((size_t)N * 128 * 2);
    uint16_t* h4    = aggrB;   // alias: aggrB dead after layer-2 GEMM

    int gE = (E + 255) / 256;
    int nb = (N + 1023) / 1024;
    int gNode = (N + 3) / 4;
    int g128 = (N + 127) / 128;
    int g256 = (N + 255) / 256;
    int g512 = (N + 511) / 512;

    // CSR build
    hipMemsetAsync(deg, 0, (size_t)N * 4, stream);
    k_count<<<gE, 256, 0, stream>>>(dst, E, deg);
    k_block_sums<<<nb, 256, 0, stream>>>(deg, N, bsum);
    k_scan_bsums<<<1, 256, 0, stream>>>(bsum, nb);
    k_scan_final<<<nb, 256, 0, stream>>>(deg, N, bsum, offs, cursor);
    k_scatter<<<gE, 256, 0, stream>>>(src, dst, E, cursor, csr);

    // fused weight prep
    PrepAll P;
    int cum = 0;
    auto seg = [&](int i, const float* W, uint16_t* wt, int K, int Dreal, int Dpad, int koff, int ldk) {
        P.s[i] = {W, wt, K, Dreal, koff, ldk, cum, cum + Dpad * K};
        cum += Dpad * K;
    };
    seg(0, s1_wl, wt1,             128, 128, 128, 0,   128);
    seg(1, s1_wr, wt1 + 128 * 128, 128, 128, 128, 0,   128);
    seg(2, s2_wl, wt2,             128, 256, 256, 0,   256);
    seg(3, s2_wr, wt2,             128, 256, 256, 128, 256);
    seg(4, s3_wl, wt3,             256, 128, 128, 0,   256);
    seg(5, s3_wr, wt3 + 128 * 256, 256, 128, 128, 0,   256);
    seg(6, l1_w,  wt4,             128, 64,  64,  0,   128);
    seg(7, lo_w,  wt5,             64,  100, 128, 0,   64);
    k_prep_all<<<(cum + 255) / 256, 256, 0, stream>>>(P, cum);

    // x -> bf16
    k_f2b<<<(N * 128 / 4 + 255) / 256, 256, 0, stream>>>(x, xb, N * 128 / 4);

    // layer 1 (mean, reordered): YZ1 = xb @ [Wl1|Wr1] (+bl on Z half); h1 = LN(mean(Y1)+Z1)
    k_mf<128, 256, 128, 256, false, false, true, uint16_t><<<dim3(g256, 2), 512, 0, stream>>>(
        xb, nullptr, wt1, s1_bl, nullptr, nullptr, N, YZ);
    k_aggr_ln<<<gNode, 256, 0, stream>>>(YZ, offs, csr, ln1_g, ln1_b, N, h1);

    // layer 2 (max): aggrB = max-gather(h1); h2 = LN([aggrB|h1] @ wt2 + b2)
    k_aggr<128, true><<<gNode, 256, 0, stream>>>(h1, offs, csr, N, aggrB);
    k_mf<128, 256, 256, 128, true, true, false, uint16_t><<<dim3(g128, 1), 512, 0, stream>>>(
        aggrB, h1, wt2, s2_bl, ln2_g, ln2_b, N, h2);

    // layer 3 (mean, reordered): YZ3 = h2 @ [Wl3|Wr3] (+bl on Z half); h3 = LN(mean(Y3)+Z3)
    k_mf<256, 256, 128, 256, false, false, true, uint16_t><<<dim3(g256, 2), 512, 0, stream>>>(
        h2, nullptr, wt3, s3_bl, nullptr, nullptr, N, YZ);
    k_aggr_ln<<<gNode, 256, 0, stream>>>(YZ, offs, csr, ln3_g, ln3_b, N, h3);

    // lin1 + LN/ReLU  (512 rows x 64 cols per block, per-wave LN)
    k_mf<128, 64, 64, 512, false, true, false, uint16_t><<<dim3(g512, 1), 512, 0, stream>>>(
        h3, nullptr, wt4, l1_b, ln4_g, ln4_b, N, h4);

    // output projection (no LN), fp32 out  (256 rows x 128 cols per block)
    k_mf<64, 100, 128, 256, false, false, false, float><<<dim3(g256, 1), 512, 0, stream>>>(
        h4, nullptr, wt5, lo_b, nullptr, nullptr, N, out);
}

// Round 10
// 424.189 us; speedup vs baseline: 1.2902x; 1.2902x over previous
//
#include <hip/hip_runtime.h>
#include <stdint.h>

#define DEV __device__ __forceinline__

typedef __attribute__((ext_vector_type(8))) short bf16x8;   // 8 bf16 = 4 VGPRs
typedef __attribute__((ext_vector_type(4))) float f32x4;

// ---------- bf16 bit helpers ----------
DEV float bf2f(uint16_t u) { return __uint_as_float(((uint32_t)u) << 16); }
DEV uint16_t f2bfbits(float f) {          // round-to-nearest-even
    uint32_t x = __float_as_uint(f);
    uint32_t r = x + 0x7fffu + ((x >> 16) & 1u);
    return (uint16_t)(r >> 16);
}
DEV void stv(uint16_t* p, float v) { *p = f2bfbits(v); }
DEV void stv(float* p, float v) { *p = v; }

template<int C> DEV void ldbf(const uint16_t* p, float* f);
template<> DEV void ldbf<2>(const uint16_t* p, float* f) {
    uint32_t v = *reinterpret_cast<const uint32_t*>(p);
    f[0] = __uint_as_float(v << 16); f[1] = __uint_as_float(v & 0xffff0000u);
}
template<> DEV void ldbf<4>(const uint16_t* p, float* f) {
    uint2 v = *reinterpret_cast<const uint2*>(p);
    f[0] = __uint_as_float(v.x << 16); f[1] = __uint_as_float(v.x & 0xffff0000u);
    f[2] = __uint_as_float(v.y << 16); f[3] = __uint_as_float(v.y & 0xffff0000u);
}

// async global->LDS, 16B per lane; LDS dest = wave-uniform base + lane*16
DEV void gl16(const uint16_t* g, uint8_t* l) {
    __builtin_amdgcn_global_load_lds(
        (const __attribute__((address_space(1))) uint32_t*)g,
        (__attribute__((address_space(3))) uint32_t*)l, 16, 0, 0);
}

// counted vmcnt wait (compile-time literal; lgkm/exp untouched)
template<int N> DEV void vwait() {
    if constexpr (N == 0)      asm volatile("s_waitcnt vmcnt(0)" ::: "memory");
    else if constexpr (N == 3) asm volatile("s_waitcnt vmcnt(3)" ::: "memory");
    else if constexpr (N == 4) asm volatile("s_waitcnt vmcnt(4)" ::: "memory");
    else if constexpr (N == 6) asm volatile("s_waitcnt vmcnt(6)" ::: "memory");
    else                       asm volatile("s_waitcnt vmcnt(0)" ::: "memory");
}

// ---------------------- CSR build ----------------------
__global__ void k_count(const int* __restrict__ dst, int e, int* __restrict__ deg) {
    int i = blockIdx.x * 256 + threadIdx.x;
    if (i < e) atomicAdd(&deg[dst[i]], 1);
}

__global__ void k_block_sums(const int* __restrict__ deg, int n, int* __restrict__ bsum) {
    __shared__ int sm[256];
    int base = blockIdx.x * 1024;
    int s = 0;
    for (int i = threadIdx.x; i < 1024; i += 256) {
        int g = base + i;
        if (g < n) s += deg[g];
    }
    sm[threadIdx.x] = s; __syncthreads();
    for (int o = 128; o > 0; o >>= 1) {
        if (threadIdx.x < o) sm[threadIdx.x] += sm[threadIdx.x + o];
        __syncthreads();
    }
    if (threadIdx.x == 0) bsum[blockIdx.x] = sm[0];
}

__global__ void k_scan_bsums(int* bsum, int nb) {
    __shared__ int sm[256];
    int t = threadIdx.x;
    int v = (t < nb) ? bsum[t] : 0;
    sm[t] = v; __syncthreads();
    for (int o = 1; o < 256; o <<= 1) {
        int add = (t >= o) ? sm[t - o] : 0;
        __syncthreads();
        sm[t] += add;
        __syncthreads();
    }
    if (t < nb) bsum[t] = (t == 0) ? 0 : sm[t - 1];
}

__global__ void k_scan_final(const int* __restrict__ deg, int n,
                             const int* __restrict__ bsum, int* __restrict__ offs,
                             int* __restrict__ cursor) {
    __shared__ int sm[256];
    int t = threadIdx.x;
    int i0 = blockIdx.x * 1024 + t * 4;
    int d0 = (i0     < n) ? deg[i0]     : 0;
    int d1 = (i0 + 1 < n) ? deg[i0 + 1] : 0;
    int d2 = (i0 + 2 < n) ? deg[i0 + 2] : 0;
    int d3 = (i0 + 3 < n) ? deg[i0 + 3] : 0;
    int ts = d0 + d1 + d2 + d3;
    sm[t] = ts; __syncthreads();
    for (int o = 1; o < 256; o <<= 1) {
        int add = (t >= o) ? sm[t - o] : 0;
        __syncthreads();
        sm[t] += add;
        __syncthreads();
    }
    int e0 = bsum[blockIdx.x] + ((t == 0) ? 0 : sm[t - 1]);
    int e1 = e0 + d0, e2 = e1 + d1, e3 = e2 + d2, e4 = e3 + d3;
    if (i0     < n) { offs[i0]     = e0; cursor[i0]     = e0; }
    if (i0 + 1 < n) { offs[i0 + 1] = e1; cursor[i0 + 1] = e1; }
    if (i0 + 2 < n) { offs[i0 + 2] = e2; cursor[i0 + 2] = e2; }
    if (i0 + 3 < n) { offs[i0 + 3] = e3; cursor[i0 + 3] = e3; }
    if (i0 <= n - 1 && n - 1 < i0 + 4) offs[n] = e4;  // total
}

__global__ void k_scatter(const int* __restrict__ src, const int* __restrict__ dst, int e,
                          int* __restrict__ cursor, int* __restrict__ csr) {
    int i = blockIdx.x * 256 + threadIdx.x;
    if (i < e) {
        int p = atomicAdd(&cursor[dst[i]], 1);
        csr[p] = src[i];
    }
}

// ---------------------- fp32 -> bf16 convert ----------------------
__global__ void k_f2b(const float* __restrict__ in, uint16_t* __restrict__ o, int n4) {
    int i = blockIdx.x * 256 + threadIdx.x;
    if (i < n4) {
        float4 v = reinterpret_cast<const float4*>(in)[i];
        uint2 w;
        w.x = f2bfbits(v.x) | ((uint32_t)f2bfbits(v.y) << 16);
        w.y = f2bfbits(v.z) | ((uint32_t)f2bfbits(v.w) << 16);
        reinterpret_cast<uint2*>(o)[i] = w;
    }
}

// ---------------------- fused weight prep: transpose fp32 [K][Dreal] -> bf16 wt[n][koff+k] ----------------------
struct PrepSeg { const float* W; uint16_t* wt; int K, Dreal, koff, ldk, start, end; };
struct PrepAll { PrepSeg s[8]; };

__global__ void k_prep_all(PrepAll P, int total) {
    int idx = blockIdx.x * 256 + threadIdx.x;
    if (idx >= total) return;
#pragma unroll
    for (int i = 0; i < 8; ++i) {
        if (idx >= P.s[i].start && idx < P.s[i].end) {
            int loc = idx - P.s[i].start;
            int K = P.s[i].K;
            int nn = loc / K, k = loc - nn * K;
            float v = (nn < P.s[i].Dreal) ? P.s[i].W[(size_t)k * P.s[i].Dreal + nn] : 0.f;
            P.s[i].wt[(size_t)nn * P.s[i].ldk + P.s[i].koff + k] = f2bfbits(v);
        }
    }
}

// ---------------------- max-aggregation (bf16 in/out) ----------------------
template<int D, bool MAXAGG>
__global__ __launch_bounds__(256) void k_aggr(const uint16_t* __restrict__ X,
                                              const int* __restrict__ offs,
                                              const int* __restrict__ csr,
                                              int n, uint16_t* __restrict__ out) {
    constexpr int C = D / 64;
    int lane = threadIdx.x & 63;
    int node = blockIdx.x * 4 + (threadIdx.x >> 6);
    if (node >= n) return;
    int beg = offs[node], end = offs[node + 1];
    float acc[C];
#pragma unroll
    for (int c = 0; c < C; c++) acc[c] = 0.f;
    const size_t loff = (size_t)lane * C;
    int i = beg;
    for (; i + 3 < end; i += 4) {             // 4 gathers in flight
        int s0 = csr[i], s1 = csr[i + 1], s2 = csr[i + 2], s3 = csr[i + 3];
        float f0[C], f1[C], f2[C], f3[C];
        ldbf<C>(X + (size_t)s0 * D + loff, f0);
        ldbf<C>(X + (size_t)s1 * D + loff, f1);
        ldbf<C>(X + (size_t)s2 * D + loff, f2);
        ldbf<C>(X + (size_t)s3 * D + loff, f3);
#pragma unroll
        for (int c = 0; c < C; c++) {
            if (MAXAGG) {
                acc[c] = fmaxf(acc[c], fmaxf(fmaxf(f0[c], f1[c]), fmaxf(f2[c], f3[c])));
            } else {
                acc[c] += (f0[c] + f1[c]) + (f2[c] + f3[c]);
            }
        }
    }
    for (; i < end; ++i) {
        int s = csr[i];
        float f[C];
        ldbf<C>(X + (size_t)s * D + loff, f);
#pragma unroll
        for (int c = 0; c < C; c++)
            acc[c] = MAXAGG ? fmaxf(acc[c], f[c]) : (acc[c] + f[c]);
    }
    int d = end - beg; if (d < 1) d = 1;
    float scale = MAXAGG ? 1.f : (1.f / (float)d);
    uint16_t* q = out + (size_t)node * D + loff;
    if constexpr (C == 2) {
        uint32_t v = f2bfbits(acc[0] * scale) | ((uint32_t)f2bfbits(acc[1] * scale) << 16);
        *reinterpret_cast<uint32_t*>(q) = v;
    } else {
        uint2 v;
        v.x = f2bfbits(acc[0] * scale) | ((uint32_t)f2bfbits(acc[1] * scale) << 16);
        v.y = f2bfbits(acc[2] * scale) | ((uint32_t)f2bfbits(acc[3] * scale) << 16);
        *reinterpret_cast<uint2*>(q) = v;
    }
}

// ---------------------- mean-aggregate(Y) + Z + LN + ReLU  (SAGE-mean reordered) ----------------------
// YZ = [N][256] bf16: cols 0-127 = Y = X@Wl, cols 128-255 = Z = X@Wr + bl.
__global__ __launch_bounds__(256) void k_aggr_ln(const uint16_t* __restrict__ YZ,
                                                 const int* __restrict__ offs,
                                                 const int* __restrict__ csr,
                                                 const float* __restrict__ g,
                                                 const float* __restrict__ b,
                                                 int n, uint16_t* __restrict__ out) {
    int lane = threadIdx.x & 63;
    int node = blockIdx.x * 4 + (threadIdx.x >> 6);
    if (node >= n) return;
    int beg = offs[node], end = offs[node + 1];
    float a0 = 0.f, a1 = 0.f;
    const size_t loff = (size_t)lane * 2;
    int i = beg;
    for (; i + 3 < end; i += 4) {             // 4 gathers in flight
        int s0 = csr[i], s1 = csr[i + 1], s2 = csr[i + 2], s3 = csr[i + 3];
        float f0[2], f1[2], f2[2], f3[2];
        ldbf<2>(YZ + (size_t)s0 * 256 + loff, f0);
        ldbf<2>(YZ + (size_t)s1 * 256 + loff, f1);
        ldbf<2>(YZ + (size_t)s2 * 256 + loff, f2);
        ldbf<2>(YZ + (size_t)s3 * 256 + loff, f3);
        a0 += (f0[0] + f1[0]) + (f2[0] + f3[0]);
        a1 += (f0[1] + f1[1]) + (f2[1] + f3[1]);
    }
    for (; i < end; ++i) {
        int s = csr[i];
        float f[2];
        ldbf<2>(YZ + (size_t)s * 256 + loff, f);
        a0 += f[0]; a1 += f[1];
    }
    int d = end - beg; if (d < 1) d = 1;
    float scale = 1.f / (float)d;
    float z[2];
    ldbf<2>(YZ + (size_t)node * 256 + 128 + loff, z);
    float v0 = a0 * scale + z[0];
    float v1 = a1 * scale + z[1];
    float s = v0 + v1, s2 = v0 * v0 + v1 * v1;
#pragma unroll
    for (int o = 1; o < 64; o <<= 1) { s += __shfl_xor(s, o); s2 += __shfl_xor(s2, o); }
    float mean = s * (1.f / 128.f);
    float var = s2 * (1.f / 128.f) - mean * mean;
    float inv = rsqrtf(var + 1e-5f);
    float y0 = fmaxf((v0 - mean) * inv * g[loff]     + b[loff],     0.f);
    float y1 = fmaxf((v1 - mean) * inv * g[loff + 1] + b[loff + 1], 0.f);
    uint32_t w = f2bfbits(y0) | ((uint32_t)f2bfbits(y1) << 16);
    *reinterpret_cast<uint32_t*>(out + (size_t)node * 128 + loff) = w;
}

// ---------------------- MFMA GEMM: triple-buffered DMA staging + counted vmcnt ----------------------
// block = 128 rows x DB cols; 4 waves, wave = 32 rows x DB cols (R4 geometry, 424us-best).
// Pipeline (T3/T4): stage(s) issued 2 steps ahead into lds[s%3]. Per step:
//   s_waitcnt vmcnt(L)   (own stage-s loads landed; newest stage's L stay in flight)
//   s_barrier            (=> ALL waves' stage-s loads landed; buf (s-1)%3 reads all done)
//   sched_barrier(0)     (pin ds_reads below the wait/barrier — rule 18)
//   stage(s+2) -> lds[(s+2)%3]  (== buf (s-1)%3, safe per barrier)
//   ds_read + 2*NF MFMA on lds[s%3]
// A frag: row=lane&15, k=(lane>>4)*8+j ; B frag: col=lane&15 ; C/D: col=lane&15, row=(lane>>4)*4+reg.
// ZBIAS: bias applied only to cols >= DOUT/2 (the Z half of a [Y|Z] dual-output GEMM).
template<int KPER, int DOUT, int DB, bool DUAL, bool LN, bool ZBIAS, typename TO>
__global__ __launch_bounds__(256) void k_mf(const uint16_t* __restrict__ A0,
                                            const uint16_t* __restrict__ A1,
                                            const uint16_t* __restrict__ WT,
                                            const float* __restrict__ bias,
                                            const float* __restrict__ g,
                                            const float* __restrict__ bvec,
                                            int n, TO* __restrict__ out) {
    constexpr int KEFF = KPER * (DUAL ? 2 : 1);
    constexpr int NST = KEFF / 32;        // k-steps
    constexpr int NF = DB / 16;
    constexpr int WPL = DB * 16;          // W plane bytes per 8-k chunk
    constexpr int AB = 8192;              // A tile bytes (128 rows x 32 k x 2B)
    constexpr int WB = DB * 64;           // W tile bytes (DB cols x 32 k x 2B)
    constexpr int HB = DB / 64;           // W 1KB-chunks per wave (1,2,4)
    constexpr int L  = 2 + HB;            // gl16 per wave per stage
    __shared__ __align__(16) uint8_t lds[3][AB + WB];

    int tid = threadIdx.x;
    int lane = tid & 63, wid = tid >> 6;
    int lr = lane & 15, kb = lane >> 4;
    int row0 = blockIdx.x * 128;
    int wrow = wid * 32;

    auto stage = [&](int kt, uint8_t* buf) {
        const uint16_t* Asel = A0; int kk = kt;
        if (DUAL && kt >= KPER) { Asel = A1; kk = kt - KPER; }
        uint8_t* aB = buf;
        uint8_t* wB = buf + AB;
        // A tile: 8 x 1KB chunks, 2 per wave. chunk p: plane cb=p>>1, row-half h=p&1
#pragma unroll
        for (int j = 0; j < 2; ++j) {
            int p = wid * 2 + j, cb = p >> 1, h = p & 1;
            int grow = row0 + h * 64 + lane; if (grow >= n) grow = n - 1;
            gl16(Asel + (size_t)grow * KPER + kk + cb * 8, aB + cb * 2048 + h * 1024);
        }
        // W tile: DB/16 x 1KB chunks, HB per wave. chunk p: cb=p/HB, col-half h=p%HB
#pragma unroll
        for (int j = 0; j < HB; ++j) {
            int p = wid * HB + j, cb = p / HB, h = p % HB;
            int c = h * 64 + lane;
            gl16(WT + (size_t)c * KEFF + kt + cb * 8, wB + cb * WPL + h * 1024);
        }
    };

    f32x4 acc[2][NF] = {};
    // prologue: 2 stages in flight
    stage(0, lds[0]);
    if constexpr (NST > 1) stage(32, lds[1]);

#pragma unroll
    for (int s = 0; s < NST; ++s) {
        if (s < NST - 1) vwait<L>(); else vwait<0>();   // own stage-s loads landed
        __builtin_amdgcn_s_barrier();                    // all waves' stage-s loads landed
        __builtin_amdgcn_sched_barrier(0);               // nothing crosses upward
        if (s + 2 < NST) stage((s + 2) * 32, lds[(s + 2) % 3]);
        const uint8_t* aB = lds[s % 3];
        const uint8_t* wB = lds[s % 3] + AB;
        bf16x8 af0 = *reinterpret_cast<const bf16x8*>(aB + kb * 2048 + (wrow + lr) * 16);
        bf16x8 af1 = *reinterpret_cast<const bf16x8*>(aB + kb * 2048 + (wrow + 16 + lr) * 16);
#pragma unroll
        for (int nf = 0; nf < NF; ++nf) {
            bf16x8 wf = *reinterpret_cast<const bf16x8*>(wB + kb * WPL + (nf * 16 + lr) * 16);
            acc[0][nf] = __builtin_amdgcn_mfma_f32_16x16x32_bf16(af0, wf, acc[0][nf], 0, 0, 0);
            acc[1][nf] = __builtin_amdgcn_mfma_f32_16x16x32_bf16(af1, wf, acc[1][nf], 0, 0, 0);
        }
    }

    // ---- epilogue: bias (+ LN + ReLU), store ----
#pragma unroll
    for (int nf = 0; nf < NF; ++nf) {
        int col = nf * 16 + lr;
        float bsv;
        if constexpr (ZBIAS) {
            bsv = (col >= DOUT / 2) ? bias[col - DOUT / 2] : 0.f;
        } else {
            bsv = (DB == DOUT || col < DOUT) ? bias[col] : 0.f;
        }
#pragma unroll
        for (int r = 0; r < 4; ++r) { acc[0][nf][r] += bsv; acc[1][nf][r] += bsv; }
    }
    if constexpr (LN) {
        float gv[NF], bv2[NF];
#pragma unroll
        for (int nf = 0; nf < NF; ++nf) {
            int col = nf * 16 + lr;
            gv[nf] = g[col]; bv2[nf] = bvec[col];
        }
#pragma unroll
        for (int m = 0; m < 2; ++m) {
            float s[4], s2[4];
#pragma unroll
            for (int r = 0; r < 4; ++r) { s[r] = 0.f; s2[r] = 0.f; }
#pragma unroll
            for (int nf = 0; nf < NF; ++nf)
#pragma unroll
                for (int r = 0; r < 4; ++r) { float v = acc[m][nf][r]; s[r] += v; s2[r] += v * v; }
#pragma unroll
            for (int r = 0; r < 4; ++r) {
#pragma unroll
                for (int o = 1; o < 16; o <<= 1) {   // xor within the 16-lane col group
                    s[r] += __shfl_xor(s[r], o);
                    s2[r] += __shfl_xor(s2[r], o);
                }
                float mean = s[r] / DOUT;
                float var = s2[r] / DOUT - mean * mean;
                float inv = rsqrtf(var + 1e-5f);
#pragma unroll
                for (int nf = 0; nf < NF; ++nf) {
                    float y = (acc[m][nf][r] - mean) * inv * gv[nf] + bv2[nf];
                    acc[m][nf][r] = fmaxf(y, 0.f);
                }
            }
        }
    }
#pragma unroll
    for (int m = 0; m < 2; ++m)
#pragma unroll
        for (int r = 0; r < 4; ++r) {
            int row = row0 + wrow + m * 16 + kb * 4 + r;
            if (row < n) {
#pragma unroll
                for (int nf = 0; nf < NF; ++nf) {
                    int col = nf * 16 + lr;
                    if (DB == DOUT || col < DOUT)
                        stv(out + (size_t)row * DOUT + col, acc[m][nf][r]);
                }
            }
        }
}

// ---------------------- launcher ----------------------
extern "C" void kernel_launch(void* const* d_in, const int* in_sizes, int n_in,
                              void* d_out, int out_size, void* d_ws, size_t ws_size,
                              hipStream_t stream) {
    const float* x     = (const float*)d_in[0];
    const int*   src   = (const int*)d_in[1];
    const int*   dst   = (const int*)d_in[2];
    const float* s1_wl = (const float*)d_in[3];
    const float* s1_bl = (const float*)d_in[4];
    const float* s1_wr = (const float*)d_in[5];
    const float* ln1_g = (const float*)d_in[6];
    const float* ln1_b = (const float*)d_in[7];
    const float* s2_wl = (const float*)d_in[8];
    const float* s2_bl = (const float*)d_in[9];
    const float* s2_wr = (const float*)d_in[10];
    const float* ln2_g = (const float*)d_in[11];
    const float* ln2_b = (const float*)d_in[12];
    const float* s3_wl = (const float*)d_in[13];
    const float* s3_bl = (const float*)d_in[14];
    const float* s3_wr = (const float*)d_in[15];
    const float* ln3_g = (const float*)d_in[16];
    const float* ln3_b = (const float*)d_in[17];
    const float* l1_w  = (const float*)d_in[18];
    const float* l1_b  = (const float*)d_in[19];
    const float* ln4_g = (const float*)d_in[20];
    const float* ln4_b = (const float*)d_in[21];
    const float* lo_w  = (const float*)d_in[22];
    const float* lo_b  = (const float*)d_in[23];
    float* out = (float*)d_out;

    const int N = in_sizes[0] / 128;
    const int E = in_sizes[1];
    (void)n_in; (void)out_size; (void)ws_size;

    char* w = (char*)d_ws;
    size_t off = 0;
    auto alloc = [&](size_t bytes) -> void* {
        void* p = w + off;
        off = (off + bytes + 255) & ~(size_t)255;
        return p;
    };
    int* deg    = (int*)alloc((size_t)N * 4);
    int* offs   = (int*)alloc((size_t)(N + 1) * 4);
    int* cursor = (int*)alloc((size_t)N * 4);
    int* bsum   = (int*)alloc(1024 * 4);
    int* csr    = (int*)alloc((size_t)E * 4);
    uint16_t* wt1 = (uint16_t*)alloc(256 * 128 * 2);   // [256][128]: rows 0-127 Wl1^T, 128-255 Wr1^T
    uint16_t* wt2 = (uint16_t*)alloc(256 * 256 * 2);   // [256][256]: K-concat [Wl2;Wr2]
    uint16_t* wt3 = (uint16_t*)alloc(256 * 256 * 2);   // [256][256]: rows 0-127 Wl3^T, 128-255 Wr3^T
    uint16_t* wt4 = (uint16_t*)alloc(64 * 128 * 2);    // [64][128]
    uint16_t* wt5 = (uint16_t*)alloc(128 * 64 * 2);    // [128][64] (cols 100..127 zero)
    uint16_t* xb    = (uint16_t*)alloc((size_t)N * 128 * 2);
    uint16_t* YZ    = (uint16_t*)alloc((size_t)N * 256 * 2);  // [Y|Z] for layers 1 and 3
    uint16_t* h1    = (uint16_t*)alloc((size_t)N * 128 * 2);
    uint16_t* aggrB = (uint16_t*)alloc((size_t)N * 128 * 2);  // max-aggr output; reused as h4
    uint16_t* h2    = (uint16_t*)alloc((size_t)N * 256 * 2);
    uint16_t* h3    = (uint16_t*)alloc((size_t)N * 128 * 2);
    uint16_t* h4    = aggrB;   // alias: aggrB dead after layer-2 GEMM

    int gE = (E + 255) / 256;
    int nb = (N + 1023) / 1024;
    int gNode = (N + 3) / 4;
    int g128 = (N + 127) / 128;

    // CSR build
    hipMemsetAsync(deg, 0, (size_t)N * 4, stream);
    k_count<<<gE, 256, 0, stream>>>(dst, E, deg);
    k_block_sums<<<nb, 256, 0, stream>>>(deg, N, bsum);
    k_scan_bsums<<<1, 256, 0, stream>>>(bsum, nb);
    k_scan_final<<<nb, 256, 0, stream>>>(deg, N, bsum, offs, cursor);
    k_scatter<<<gE, 256, 0, stream>>>(src, dst, E, cursor, csr);

    // fused weight prep
    PrepAll P;
    int cum = 0;
    auto seg = [&](int i, const float* W, uint16_t* wt, int K, int Dreal, int Dpad, int koff, int ldk) {
        P.s[i] = {W, wt, K, Dreal, koff, ldk, cum, cum + Dpad * K};
        cum += Dpad * K;
    };
    seg(0, s1_wl, wt1,             128, 128, 128, 0,   128);
    seg(1, s1_wr, wt1 + 128 * 128, 128, 128, 128, 0,   128);
    seg(2, s2_wl, wt2,             128, 256, 256, 0,   256);
    seg(3, s2_wr, wt2,             128, 256, 256, 128, 256);
    seg(4, s3_wl, wt3,             256, 128, 128, 0,   256);
    seg(5, s3_wr, wt3 + 128 * 256, 256, 128, 128, 0,   256);
    seg(6, l1_w,  wt4,             128, 64,  64,  0,   128);
    seg(7, lo_w,  wt5,             64,  100, 128, 0,   64);
    k_prep_all<<<(cum + 255) / 256, 256, 0, stream>>>(P, cum);

    // x -> bf16
    k_f2b<<<(N * 128 / 4 + 255) / 256, 256, 0, stream>>>(x, xb, N * 128 / 4);

    // layer 1 (mean, reordered): YZ1 = xb @ [Wl1|Wr1] (+bl on Z half); h1 = LN(mean(Y1)+Z1)
    k_mf<128, 256, 256, false, false, true, uint16_t><<<g128, 256, 0, stream>>>(
        xb, nullptr, wt1, s1_bl, nullptr, nullptr, N, YZ);
    k_aggr_ln<<<gNode, 256, 0, stream>>>(YZ, offs, csr, ln1_g, ln1_b, N, h1);

    // layer 2 (max): aggrB = max-gather(h1); h2 = LN([aggrB|h1] @ wt2 + b2)
    k_aggr<128, true><<<gNode, 256, 0, stream>>>(h1, offs, csr, N, aggrB);
    k_mf<128, 256, 256, true, true, false, uint16_t><<<g128, 256, 0, stream>>>(
        aggrB, h1, wt2, s2_bl, ln2_g, ln2_b, N, h2);

    // layer 3 (mean, reordered): YZ3 = h2 @ [Wl3|Wr3] (+bl on Z half); h3 = LN(mean(Y3)+Z3)
    k_mf<256, 256, 256, false, false, true, uint16_t><<<g128, 256, 0, stream>>>(
        h2, nullptr, wt3, s3_bl, nullptr, nullptr, N, YZ);
    k_aggr_ln<<<gNode, 256, 0, stream>>>(YZ, offs, csr, ln3_g, ln3_b, N, h3);

    // lin1 + LN/ReLU
    k_mf<128, 64, 64, false, true, false, uint16_t><<<g128, 256, 0, stream>>>(
        h3, nullptr, wt4, l1_b, ln4_g, ln4_b, N, h4);

    // output projection (no LN), fp32 out
    k_mf<64, 100, 128, false, false, false, float><<<g128, 256, 0, stream>>>(
        h4, nullptr, wt5, lo_b, nullptr, nullptr, N, out);
}